// Round 8
// baseline (1156.772 us; speedup 1.0000x reference)
//
#include <hip/hip_runtime.h>

// ---------------------------------------------------------------------------
// Encoder: feature/temporal regression + temporal-decay LSTM scan + L1 loss
// B=512 T=128 F=128 H=256.  Outputs: h[512,256], c[512,256], loss (fp32).
//
// R7 -> R8: software-pipelined cold loads in kscan (single variable).
//  Theory: the ~6 us/step floor across six structural variants is the cold
//  HBM latency of x/g/values/masks loads consumed same-step with 1 wave/SIMD
//  (zero TLP). Fix: double-buffer xr/gr/vv/mm in registers; at step t issue
//  the t+1 loads right AFTER the poll + hr loads (vmcnt is IN-ORDER: newer
//  prefetches don't block hr's s_waitcnt, but anything issued before the
//  poll/hr loads would). Issue point pinned with an asm memory clobber.
//  The end-of-step vmcnt(0) (required before the flag store) also drains the
//  prefetches - residual stall accepted this round.
//  Heaters removed (R7 proved them neutral): grid back to 128.
// ---------------------------------------------------------------------------

typedef _Float16 f16;
typedef _Float16 half8 __attribute__((ext_vector_type(8)));
typedef float f32x4 __attribute__((ext_vector_type(4)));

#define B_ 512
#define T_ 128
#define F_ 128
#define H_ 256
#define NSTEP 127
#define PV 136     // LDS row stride f16 for k1/k2 tiles
#define PW 264     // LDS row stride f16 for W_ih slice
#define FLAG_STRIDE 16   // dwords: one 64B line per producer wave

__device__ __forceinline__ float sigm(float x){ return 1.f/(1.f + __expf(-x)); }
__device__ __forceinline__ float tanh_(float x){
  float e = __expf(-2.f*fabsf(x));
  float t = (1.f - e)/(1.f + e);
  return x >= 0.f ? t : -t;
}

// ---------------------------------------------------------------------------
__global__ void kprep(const float* __restrict__ Wih, const float* __restrict__ Whh,
                      const float* __restrict__ outW,
                      const float* __restrict__ featW, const float* __restrict__ tempW,
                      const float* __restrict__ decW,
                      f16* __restrict__ Wt, f16* __restrict__ oWh,
                      f16* __restrict__ fWh, f16* __restrict__ tWh,
                      f16* __restrict__ dWh, unsigned int* __restrict__ flags,
                      float* __restrict__ accums)
{
  int idx = blockIdx.x*256 + threadIdx.x;
  int stride = gridDim.x*256;
  // W_cat[zc][k]: k<256 -> W_ih[zc][k] (inp = [values_hat, masks]); k>=256 -> W_hh
  for (int i = idx; i < 1024*512; i += stride){
    int zc = i >> 9, k = i & 511;
    float w = (k < 256) ? Wih[zc*256 + k] : Whh[zc*256 + k - 256];
    Wt[i] = (f16)w;
  }
  for (int i = idx; i < 128*256; i += stride) oWh[i] = (f16)outW[i];
  // fWh[fo][gi] = feat_W[fo][gi], diag zeroed (B-frag layout)
  for (int i = idx; i < 128*128; i += stride){
    int fo = i >> 7, gi = i & 127;
    fWh[i] = (fo == gi) ? (f16)0.f : (f16)featW[i];
  }
  // tWh[t][s] = temp_W[t][s], diag zeroed (A-frag layout)
  for (int i = idx; i < 128*128; i += stride){
    int t = i >> 7, s = i & 127;
    tWh[i] = (s == t) ? (f16)0.f : (f16)tempW[i];
  }
  for (int i = idx; i < 256*128; i += stride) dWh[i] = (f16)decW[i];
  for (int i = idx; i < 512*FLAG_STRIDE; i += stride) flags[i] = 0u;
  if (idx < 2) accums[idx] = 0.f;
}

// ---------------------------------------------------------------------------
__global__ __launch_bounds__(256) void kdenom(const float* __restrict__ masks,
                                              float* __restrict__ dinv)
{
  int t = blockIdx.x;
  __shared__ float red[256];
  float s = 0.f;
  for (int i = threadIdx.x; i < B_*F_; i += 256){
    int b = i >> 7, f = i & 127;
    s += masks[((size_t)b << 14) + (t << 7) + f];
  }
  red[threadIdx.x] = s; __syncthreads();
  for (int o = 128; o > 0; o >>= 1){
    if (threadIdx.x < o) red[threadIdx.x] += red[threadIdx.x + o];
    __syncthreads();
  }
  if (threadIdx.x == 0) dinv[t] = 1.f/(red[0] + 1e-5f);
}

// ---------------------------------------------------------------------------
// k1 (MFMA): per batch b, C[t][f] = sum_g V[t][g]*featW[f][g](masked)
//                                  + sum_s tWm[t][s]*V[s][f]  + feat_b[f] + temp_b[t]
// x = (m!=0) ? v : C ; x_all[t][b][0:128]=x, [128:256]=m  (masks are exact 0/1)
__global__ __launch_bounds__(256) void k1(
    const float* __restrict__ values, const float* __restrict__ masks,
    const f16* __restrict__ fWh, const f16* __restrict__ tWh,
    const float* __restrict__ featb, const float* __restrict__ tempb,
    f16* __restrict__ x_all)
{
  extern __shared__ char sm1[];
  f16* V  = (f16*)sm1;                   // [128][PV]  row t, contig f
  f16* Vt = (f16*)(sm1 + 128*PV*2);      // [128][PV]  row f, contig t (transposed)
  const int b = blockIdx.x, tid = threadIdx.x;
  const float* vb = values + ((size_t)b << 14);

  for (int i = tid; i < 8192; i += 256){
    int f = i & 127, tp = i >> 7;      // tp = t/2
    float a = vb[(tp*2)*128 + f];
    float c = vb[(tp*2+1)*128 + f];
    f16 ha = (f16)a, hc = (f16)c;
    V[(tp*2)*PV + f]   = ha;
    V[(tp*2+1)*PV + f] = hc;
    union { f16 h[2]; unsigned u; } pk; pk.h[0] = ha; pk.h[1] = hc;
    *(unsigned*)(Vt + f*PV + tp*2) = pk.u;
  }
  __syncthreads();

  const int w = tid >> 6, lane = tid & 63, lrow = lane & 15, lq = lane >> 4;
  for (int ti2 = 0; ti2 < 2; ++ti2){
    const int t0 = (w*2 + ti2) << 4;
    half8 aV[4], aT[4];
#pragma unroll
    for (int kk = 0; kk < 4; ++kk){
      aV[kk] = *(const half8*)(V + (t0+lrow)*PV + kk*32 + lq*8);
      aT[kk] = *(const half8*)(tWh + (t0+lrow)*128 + kk*32 + lq*8);
    }
    float tb[4];
#pragma unroll
    for (int r = 0; r < 4; ++r) tb[r] = tempb[t0 + lq*4 + r];
#pragma unroll
    for (int fj = 0; fj < 8; ++fj){
      const int f0 = fj << 4;
      f32x4 acc = {0.f,0.f,0.f,0.f};
#pragma unroll
      for (int kk = 0; kk < 4; ++kk){
        half8 bF = *(const half8*)(fWh + (f0+lrow)*128 + kk*32 + lq*8);
        half8 bT = *(const half8*)(Vt  + (f0+lrow)*PV  + kk*32 + lq*8);
        acc = __builtin_amdgcn_mfma_f32_16x16x32_f16(aV[kk], bF, acc, 0,0,0);
        acc = __builtin_amdgcn_mfma_f32_16x16x32_f16(aT[kk], bT, acc, 0,0,0);
      }
      const float fb = featb[f0 + lrow];
#pragma unroll
      for (int r = 0; r < 4; ++r){
        int t = t0 + lq*4 + r, f = f0 + lrow;
        float vh = acc[r] + fb + tb[r];
        float v = (float)V[t*PV + f];
        float m = masks[((size_t)b << 14) + t*128 + f];
        float x = (m != 0.0f) ? v : vh;
        size_t o = (((size_t)t*B_ + b) << 8);
        x_all[o + f]       = (f16)x;
        x_all[o + 128 + f] = (f16)m;
      }
    }
  }
}

// ---------------------------------------------------------------------------
__global__ __launch_bounds__(256) void k2(
    const float* __restrict__ deltas, const f16* __restrict__ dWh,
    const float* __restrict__ decb, f16* __restrict__ g_all)
{
  __shared__ f16 D[128*PV];
  const int b = blockIdx.x, tid = threadIdx.x;
  const float* dp = deltas + ((size_t)b << 14);
  for (int i = tid; i < 8192; i += 256){
    int t = i >> 6, fd = (i & 63) << 1;
    float a = dp[t*128 + fd], c = dp[t*128 + fd + 1];
    union { f16 h[2]; unsigned u; } pk; pk.h[0] = (f16)a; pk.h[1] = (f16)c;
    *(unsigned*)(D + t*PV + fd) = pk.u;
  }
  __syncthreads();

  const int w = tid >> 6, lane = tid & 63, lrow = lane & 15, lq = lane >> 4;
  for (int ti2 = 0; ti2 < 2; ++ti2){
    const int t0 = (w*2 + ti2) << 4;
    half8 aD[4];
#pragma unroll
    for (int kk = 0; kk < 4; ++kk)
      aD[kk] = *(const half8*)(D + (t0+lrow)*PV + kk*32 + lq*8);
#pragma unroll
    for (int hj = 0; hj < 16; ++hj){
      const int h0 = hj << 4;
      f32x4 acc = {0.f,0.f,0.f,0.f};
#pragma unroll
      for (int kk = 0; kk < 4; ++kk){
        half8 bD = *(const half8*)(dWh + (h0+lrow)*128 + kk*32 + lq*8);
        acc = __builtin_amdgcn_mfma_f32_16x16x32_f16(aD[kk], bD, acc, 0,0,0);
      }
      const float db = decb[h0 + lrow];
#pragma unroll
      for (int r = 0; r < 4; ++r){
        int t = t0 + lq*4 + r, h = h0 + lrow;
        float gv = __expf(-fabsf(acc[r] + db));
        g_all[(((size_t)t*B_ + b) << 8) + h] = (f16)gv;
      }
    }
  }
}

// ---------------------------------------------------------------------------
// Barrier-free persistent scan (R6 dataflow) + register double-buffered
// prefetch of next-step x/gamma/loss operands. grid=128: gid=blockIdx&31,
// q=blockIdx>>5. Wave wv of WG q owns h-cols jcol=q*64+wv*16+[0,16) for ALL
// 4 gates -> wave-local cell update, no barriers in the t-loop.
__global__ __launch_bounds__(256, 1) void kscan(
    const f16* __restrict__ x_all, const f16* __restrict__ g_all,
    const f16* __restrict__ Wt, const f16* __restrict__ oWh,
    const float* __restrict__ bih, const float* __restrict__ bhh,
    const float* __restrict__ outb,
    const float* __restrict__ values, const float* __restrict__ masks,
    const float* __restrict__ dinv,
    f16* __restrict__ h_buf, unsigned int* __restrict__ flags,
    float* __restrict__ loss_accum, float* __restrict__ d_out)
{
  extern __shared__ f16 Wl[];   // [256][PW]: W_ih rows for this WG's 256 z-cols

  const int tid = threadIdx.x;
  const int gid = blockIdx.x & 31;
  const int q   = blockIdx.x >> 5;
  const int b_base = gid << 4;
  const int wv = tid >> 6, lane = tid & 63, lrow = lane & 15, lq = lane >> 4;

  // stage W_ih slice: LDS row r = w*64 + g*16 + l  <->  zc = g*256 + q*64 + w*16 + l
  for (int i = tid; i < 256*32; i += 256){
    int r = i >> 5, seg = i & 31;
    int w = r >> 6, g = (r >> 4) & 3, l = r & 15;
    int zc = (g << 8) + (q << 6) + (w << 4) + l;
    *(uint4*)(Wl + r*PW + seg*8) = *(const uint4*)(Wt + zc*512 + seg*8);
  }
  __syncthreads();   // once, at startup only

  const int jcol = (q << 6) + (wv << 4) + lrow;   // this lane's h-col
  const int arow = b_base + lrow;                 // A-frag row (batch)

  // W_hh B-frags in registers: gate g, K-chunk kk (K=256..511 of Wt rows)
  half8 wh[4][8];
#pragma unroll
  for (int g = 0; g < 4; ++g)
#pragma unroll
    for (int kk = 0; kk < 8; ++kk)
      wh[g][kk] = *(const half8*)(Wt + ((g<<8) + jcol)*512 + 256 + kk*32 + (lq<<3));

  float bias[4];
#pragma unroll
  for (int g = 0; g < 4; ++g) bias[g] = bih[(g<<8) + jcol] + bhh[(g<<8) + jcol];

  // loss: waves 0,1 of each WG handle f-tile f0 = (q*2+wv)*16 (8 tiles total)
  const bool doLoss = (wv < 2);
  const int f0 = ((q<<1) + wv) << 4;
  half8 ow[8];
  float ob = 0.f;
  if (doLoss){
#pragma unroll
    for (int kk = 0; kk < 8; ++kk)
      ow[kk] = *(const half8*)(oWh + (f0+lrow)*256 + kk*32 + (lq<<3));
    ob = outb[f0 + lrow];
  }

  float c[4] = {0.f,0.f,0.f,0.f};
  float lossAcc = 0.f;

  // per-wave flag lines; lanes (lane&15) poll the 16 producer waves
  volatile const unsigned int* pollflag = flags + ((gid<<4) + lrow)*FLAG_STRIDE;
  volatile unsigned int* ourflag = flags + ((gid<<4) + (q<<2) + wv)*FLAG_STRIDE;

  // ---- pipeline registers: current-step operands (loaded one step ahead) ----
  half8 xc[8], gc[8], xn[8], gn[8];
  float vvc[4], mmc[4], vvn[4], mmn[4];
  {
    const f16* xp = x_all + ((size_t)arow << 8) + (lq << 3);   // t=0
    const f16* gp = g_all + ((size_t)arow << 8) + (lq << 3);
#pragma unroll
    for (int kk = 0; kk < 8; ++kk) xc[kk] = *(const half8*)(xp + (kk<<5));
#pragma unroll
    for (int kk = 0; kk < 8; ++kk) gc[kk] = *(const half8*)(gp + (kk<<5));
#pragma unroll
    for (int r = 0; r < 4; ++r){ vvc[r] = 0.f; mmc[r] = 0.f; }
  }

  for (int t = 0; t < NSTEP; ++t){
    // ---- wait for h(t) first: poll loads must precede prefetch issue
    // (vmcnt is in-order; loads issued after HBM prefetches would wait on them)
    if (t > 0){
      int guard = 0;
      while (__ballot((int)(*pollflag < (unsigned)t)) != 0ull && guard < 4000000)
        ++guard;
      __builtin_amdgcn_fence(__ATOMIC_ACQUIRE, "agent");   // per-wave L1 inv
    }

    // ---- hr loads (L2-hit) issued before prefetches for the same reason
    half8 hr[8];
    if (t > 0){
      const f16* hp = h_buf + ((((t&1)*B_) + arow) << 8) + (lq << 3);
#pragma unroll
      for (int kk = 0; kk < 8; ++kk) hr[kk] = *(const half8*)(hp + (kk<<5));
    }

    // ---- issue t+1 prefetches (t+1 <= 127 is always a valid buffer index;
    // x_all/g_all/values/masks all have a t=127 slice). Pinned here.
    {
      const f16* xp = x_all + (((size_t)(t+1)*B_ + arow) << 8) + (lq << 3);
      const f16* gp = g_all + (((size_t)(t+1)*B_ + arow) << 8) + (lq << 3);
#pragma unroll
      for (int kk = 0; kk < 8; ++kk) xn[kk] = *(const half8*)(xp + (kk<<5));
#pragma unroll
      for (int kk = 0; kk < 8; ++kk) gn[kk] = *(const half8*)(gp + (kk<<5));
      if (doLoss){
#pragma unroll
        for (int r = 0; r < 4; ++r){
          size_t o = ((size_t)(b_base + (lq<<2) + r) << 14) + ((t+1) << 7) + f0 + lrow;
          vvn[r] = values[o]; mmn[r] = masks[o];
        }
      }
      asm volatile("" ::: "memory");   // pin prefetch issue point
    }

    f32x4 acc[4];
#pragma unroll
    for (int g = 0; g < 4; ++g){ acc[g][0]=bias[g]; acc[g][1]=bias[g]; acc[g][2]=bias[g]; acc[g][3]=bias[g]; }

    // x half (K=0..255): operands already in registers, no memory wait
#pragma unroll
    for (int g = 0; g < 4; ++g){
      const f16* wb = Wl + ((wv<<6) + (g<<4) + lrow)*PW + (lq<<3);
#pragma unroll
      for (int kk = 0; kk < 8; ++kk){
        half8 bx = *(const half8*)(wb + (kk<<5));
        acc[g] = __builtin_amdgcn_mfma_f32_16x16x32_f16(xc[kk], bx, acc[g], 0,0,0);
      }
    }

    if (t > 0){
      // h half: waits hr only (vmcnt(16): the 16 newer prefetches stay in flight)
      f32x4 accL = {0.f,0.f,0.f,0.f};
      if (doLoss){
#pragma unroll
        for (int kk = 0; kk < 8; ++kk)
          accL = __builtin_amdgcn_mfma_f32_16x16x32_f16(hr[kk], ow[kk], accL, 0,0,0);
      }
#pragma unroll
      for (int kk = 0; kk < 8; ++kk){
        half8 hg = hr[kk] * gc[kk];
#pragma unroll
        for (int g = 0; g < 4; ++g)
          acc[g] = __builtin_amdgcn_mfma_f32_16x16x32_f16(hg, wh[g][kk], acc[g], 0,0,0);
      }
      if (doLoss){
        float dt = dinv[t];
#pragma unroll
        for (int r = 0; r < 4; ++r)
          lossAcc += fabsf(vvc[r] - (accL[r] + ob)) * mmc[r] * dt;
      }
    }

    // ---- cell update: wave-local, 4 elems/lane (b = b_base+lq*4+r, j = jcol) ----
#pragma unroll
    for (int r = 0; r < 4; ++r){
      float zi = acc[0][r], zf = acc[1][r], zg = acc[2][r], zo = acc[3][r];
      float cn = sigm(zf)*c[r] + sigm(zi)*tanh_(zg);
      float hn = sigm(zo)*tanh_(cn);
      c[r] = cn;
      int b = b_base + (lq<<2) + r;
      if (t < NSTEP-1){
        h_buf[((((t+1)&1)*B_ + b) << 8) + jcol] = (f16)hn;
      } else {
        d_out[(b<<8) + jcol] = hn;               // h
        d_out[(1<<17) + (b<<8) + jcol] = cn;     // c
      }
    }

    if (t < NSTEP-1){
      // drain h stores (also drains this step's prefetches - they've had
      // the whole MFMA+cell span to land), then publish
      asm volatile("s_waitcnt vmcnt(0)" ::: "memory");
      if (lane == 0) *ourflag = (unsigned)(t+1);
    }

    // rotate pipeline registers
#pragma unroll
    for (int kk = 0; kk < 8; ++kk){ xc[kk] = xn[kk]; gc[kk] = gn[kk]; }
#pragma unroll
    for (int r = 0; r < 4; ++r){ vvc[r] = vvn[r]; mmc[r] = mmn[r]; }
  }

  if (doLoss){
#pragma unroll
    for (int off = 32; off > 0; off >>= 1)
      lossAcc += __shfl_down(lossAcc, off, 64);
    if (lane == 0) atomicAdd(loss_accum, lossAcc);
  }
}

// ---------------------------------------------------------------------------
__global__ __launch_bounds__(256) void kepi(
    const float* __restrict__ h_out, const float* __restrict__ outW,
    const float* __restrict__ outb, const float* __restrict__ values,
    const float* __restrict__ masks, float* __restrict__ num_final)
{
  int idx = blockIdx.x*256 + threadIdx.x;   // 65536 = 512*128
  int b = idx >> 7, f = idx & 127;
  const float* hr = h_out + (b << 8);
  const float* wr = outW + (f << 8);
  float s0 = 0.f, s1 = 0.f, s2 = 0.f, s3 = 0.f;
  for (int j = 0; j < 256; j += 4){
    s0 += hr[j]   * wr[j];
    s1 += hr[j+1] * wr[j+1];
    s2 += hr[j+2] * wr[j+2];
    s3 += hr[j+3] * wr[j+3];
  }
  float s = s0 + s1 + s2 + s3 + outb[f];
  size_t o = ((size_t)b << 14) + (127 << 7) + f;
  float term = fabsf(values[o] - s) * masks[o];
  __shared__ float red[256];
  red[threadIdx.x] = term; __syncthreads();
  for (int off = 128; off > 0; off >>= 1){
    if (threadIdx.x < off) red[threadIdx.x] += red[threadIdx.x + off];
    __syncthreads();
  }
  if (threadIdx.x == 0) atomicAdd(num_final, red[0]);
}

__global__ void kfin(const float* __restrict__ loss_accum,
                     const float* __restrict__ num_final,
                     const float* __restrict__ dinv, float* __restrict__ d_out)
{
  d_out[1<<18] = loss_accum[0] + num_final[0] * dinv[127];
}

// ---------------------------------------------------------------------------
extern "C" void kernel_launch(void* const* d_in, const int* in_sizes, int n_in,
                              void* d_out, int out_size, void* d_ws, size_t ws_size,
                              hipStream_t stream)
{
  const float* values = (const float*)d_in[0];
  const float* masks  = (const float*)d_in[1];
  const float* deltas = (const float*)d_in[2];
  const float* featW  = (const float*)d_in[3];
  const float* featb  = (const float*)d_in[4];
  const float* tempW  = (const float*)d_in[5];
  const float* tempb  = (const float*)d_in[6];
  const float* decW   = (const float*)d_in[7];
  const float* decb   = (const float*)d_in[8];
  const float* Wih    = (const float*)d_in[9];
  const float* Whh    = (const float*)d_in[10];
  const float* bih    = (const float*)d_in[11];
  const float* bhh    = (const float*)d_in[12];
  const float* outW   = (const float*)d_in[13];
  const float* outb   = (const float*)d_in[14];
  float* out = (float*)d_out;
  char* ws = (char*)d_ws;

  f16* Wt    = (f16*)(ws + 0);                 // 1 MB
  f16* oWh   = (f16*)(ws + 1048576);           // 64 KB
  f16* fWh   = (f16*)(ws + 1114112);           // 32 KB
  f16* tWh   = (f16*)(ws + 1146880);           // 32 KB
  f16* dWh   = (f16*)(ws + 1179648);           // 64 KB
  float* dinv = (float*)(ws + 1245184);        // 512 B
  unsigned int* flags = (unsigned int*)(ws + 1245696);  // 32 KB padded lines
  float* accums = (float*)(ws + 1278464);      // [0]=loss_accum [1]=num_final
  f16* h_buf = (f16*)(ws + 1278976);           // 512 KB ping-pong
  f16* x_all = (f16*)(ws + 2097152);           // 32 MB
  f16* g_all = (f16*)(ws + 35651584);          // 32 MB  (end ~66 MB)

  kprep<<<256, 256, 0, stream>>>(Wih, Whh, outW, featW, tempW, decW,
                                 Wt, oWh, fWh, tWh, dWh, flags, accums);
  kdenom<<<128, 256, 0, stream>>>(masks, dinv);

  const int S1 = 2 * 128 * PV * 2;   // V + Vt, 69632 B
  hipFuncSetAttribute((const void*)k1, hipFuncAttributeMaxDynamicSharedMemorySize, S1);
  k1<<<512, 256, S1, stream>>>(values, masks, fWh, tWh, featb, tempb, x_all);
  k2<<<512, 256, 0, stream>>>(deltas, dWh, decb, g_all);

  const int SLDS = 256 * PW * 2;   // 135168 B
  hipFuncSetAttribute((const void*)kscan, hipFuncAttributeMaxDynamicSharedMemorySize, SLDS);
  kscan<<<128, 256, SLDS, stream>>>(x_all, g_all, Wt, oWh, bih, bhh, outb,
                                    values, masks, dinv, h_buf, flags,
                                    accums, out);

  kepi<<<256, 256, 0, stream>>>(out, outW, outb, values, masks, accums + 1);
  kfin<<<1, 1, 0, stream>>>(accums, accums + 1, dinv, out);
}